// Round 3
// baseline (17413.617 us; speedup 1.0000x reference)
//
#include <hip/hip_runtime.h>

typedef __attribute__((ext_vector_type(8))) short short8;
typedef __attribute__((ext_vector_type(4))) float f32x4;

#define NSTEP 63
#define DZ 256
#define DX 64
#define DH 1024
#define NT 512

__device__ __forceinline__ unsigned short f2bf(float f){
  unsigned u = __builtin_bit_cast(unsigned, f);
  u += 0x7fffu + ((u >> 16) & 1u);
  return (unsigned short)(u >> 16);
}
__device__ __forceinline__ float bf2f(unsigned short h){
  return __builtin_bit_cast(float, (unsigned)h << 16);
}
__device__ __forceinline__ void split_bf(float v, unsigned short& h, unsigned short& l){
  h = f2bf(v);
  l = f2bf(v - bf2f(h));
}
__device__ __forceinline__ float tanh_fast(float x){
  float e = __expf(2.0f * x);
  return 1.0f - 2.0f / (e + 1.0f);
}

// Swizzled LDS access (XOR byte ^= (row&7)<<4): breaks the 16/32-way bank
// conflict of 512/2048-byte row strides on ds_read_b128; write/read use the
// same involution so it is self-consistent.
template<int ROWB>
__device__ __forceinline__ short8 ldsA(const short* buf, int row, int k0){
  int byte = row * ROWB + k0 * 2;
  byte ^= ((row & 7) << 4);
  return *reinterpret_cast<const short8*>(reinterpret_cast<const char*>(buf) + byte);
}
template<int ROWB>
__device__ __forceinline__ void ldsW16(short* buf, int row, int col, unsigned short v){
  int byte = row * ROWB + col * 2;
  byte ^= ((row & 7) << 4);
  *reinterpret_cast<short*>(reinterpret_cast<char*>(buf) + byte) = (short)v;
}

// ---------------------------------------------------------------------------
// Reformat weights into hi/lo bf16 MFMA B-fragment pairs:
//   frag(ks,nblk,p): B[k=32ks+8(l>>4)+j][col=16nblk+(l&15)], p=0 hi, p=1 lo
//   short8 index: ((ks*NB + nblk)*2 + p)*64 + lane
// ---------------------------------------------------------------------------
__global__ void reformat_weights(const float* __restrict__ W1,
                                 const float* __restrict__ W2,
                                 const float* __restrict__ Wx,
                                 short* __restrict__ W1f,
                                 short* __restrict__ W2f,
                                 short* __restrict__ Wxf){
  int tid = blockIdx.x * 256 + threadIdx.x;
  if (tid < 32768){                       // W1: ks 0..7, nblk 0..63
    int lane = tid & 63, nblk = (tid >> 6) & 63, ks = tid >> 12;
    int k0 = ks * 32 + (lane >> 4) * 8, col = nblk * 16 + (lane & 15);
    short8 vh, vl;
    #pragma unroll
    for (int j = 0; j < 8; ++j){
      unsigned short h, l; split_bf(W1[(k0 + j) * DH + col], h, l);
      vh[j] = (short)h; vl[j] = (short)l;
    }
    int base = ((ks * 64 + nblk) * 2) * 64 + lane;
    reinterpret_cast<short8*>(W1f)[base]      = vh;
    reinterpret_cast<short8*>(W1f)[base + 64] = vl;
  } else if (tid < 65536){                // W2: ks 0..31, nblk 0..15
    int t = tid - 32768;
    int lane = t & 63, nblk = (t >> 6) & 15, ks = t >> 10;
    int k0 = ks * 32 + (lane >> 4) * 8, col = nblk * 16 + (lane & 15);
    short8 vh, vl;
    #pragma unroll
    for (int j = 0; j < 8; ++j){
      unsigned short h, l; split_bf(W2[(k0 + j) * DZ + col], h, l);
      vh[j] = (short)h; vl[j] = (short)l;
    }
    int base = ((ks * 16 + nblk) * 2) * 64 + lane;
    reinterpret_cast<short8*>(W2f)[base]      = vh;
    reinterpret_cast<short8*>(W2f)[base + 64] = vl;
  } else if (tid < 73728){                // Wx: ks 0..1, nblk 0..63
    int t = tid - 65536;
    int lane = t & 63, nblk = (t >> 6) & 63, ks = t >> 12;
    int k0 = ks * 32 + (lane >> 4) * 8, col = nblk * 16 + (lane & 15);
    short8 vh, vl;
    #pragma unroll
    for (int j = 0; j < 8; ++j){
      unsigned short h, l; split_bf(Wx[(k0 + j) * DH + col], h, l);
      vh[j] = (short)h; vl[j] = (short)l;
    }
    int base = ((ks * 64 + nblk) * 2) * 64 + lane;
    reinterpret_cast<short8*>(Wxf)[base]      = vh;
    reinterpret_cast<short8*>(Wxf)[base + 64] = vl;
  }
}

// ---------------------------------------------------------------------------
// Split-precision MFMA NeuralODE: 64 WGs x 512 thr (8 waves), WG owns 16 batch
// rows, loops 63 steps x 4 stages locally. Every product a@b computed as
// a_hi@b_hi + a_hi@b_lo + a_lo@b_hi (fp32 accum) -> ~2^-18 input precision.
//   GEMM1: wave w owns h-cols [128w,128w+128): 8ks x 8nf x 3 = 192 MFMAs.
//   GEMM2: wave w owns k-cols [32w,32w+32):  32ks x 2nf x 3 = 192 MFMAs.
// ---------------------------------------------------------------------------
__global__ __launch_bounds__(NT, 1) void node_mfma(
    const float* __restrict__ z0, const float* __restrict__ tt,
    const float* __restrict__ x,
    const short* __restrict__ W1f, const short* __restrict__ W2f,
    const short* __restrict__ Wxf,
    const float* __restrict__ wt, const float* __restrict__ b1,
    const float* __restrict__ b2, float* __restrict__ out){

  const int rb   = blockIdx.x;
  const int tid  = threadIdx.x;
  const int w    = tid >> 6;
  const int lane = tid & 63;
  const int l15  = lane & 15;
  const int lq   = lane >> 4;

  __shared__ __align__(16) short zsh[16 * DZ], zsl[16 * DZ];   // 8 KB each
  __shared__ __align__(16) short hbh[16 * DH], hbl[16 * DH];   // 32 KB each
  __shared__ __align__(16) short xbh[16 * DX], xbl[16 * DX];   // 2 KB each

  const short8* W1v = reinterpret_cast<const short8*>(W1f);
  const short8* W2v = reinterpret_cast<const short8*>(W2f);
  const short8* Wxv = reinterpret_cast<const short8*>(Wxf);

  float b1r[8], wtr[8];
  #pragma unroll
  for (int nf = 0; nf < 8; ++nf){
    int c = w * 128 + nf * 16 + l15;
    b1r[nf] = b1[c]; wtr[nf] = wt[c];
  }
  float b2r[2];
  #pragma unroll
  for (int n2 = 0; n2 < 2; ++n2) b2r[n2] = b2[w * 32 + n2 * 16 + l15];

  float zb[2][4], za[2][4];
  #pragma unroll
  for (int n2 = 0; n2 < 2; ++n2){
    #pragma unroll
    for (int i = 0; i < 4; ++i){
      int row = lq * 4 + i, col = w * 32 + n2 * 16 + l15;
      zb[n2][i] = z0[(rb * 16 + row) * DZ + col];
      za[n2][i] = 0.f;
      unsigned short h, l; split_bf(zb[n2][i], h, l);
      ldsW16<512>(zsh, row, col, h);
      ldsW16<512>(zsl, row, col, l);
    }
  }

  f32x4 cx[8];

  for (int step = 0; step < NSTEP; ++step){
    const float t0 = tt[step], t1 = tt[step + 1];
    const float hs = t1 - t0;

    // stage x[step] (hi/lo bf16, swizzled): 512 thr x 2 elems
    {
      int e  = tid * 2;
      int xr = e >> 6, xc = e & 63;
      const float* xp = x + ((size_t)step * 1024 + rb * 16 + xr) * DX + xc;
      unsigned short h0, l0, h1, l1;
      split_bf(xp[0], h0, l0); split_bf(xp[1], h1, l1);
      int byte = xr * 128 + xc * 2;
      byte ^= ((xr & 7) << 4);
      *reinterpret_cast<unsigned*>(reinterpret_cast<char*>(xbh) + byte) =
          (unsigned)h0 | ((unsigned)h1 << 16);
      *reinterpret_cast<unsigned*>(reinterpret_cast<char*>(xbl) + byte) =
          (unsigned)l0 | ((unsigned)l1 << 16);
    }
    __syncthreads();

    // x-GEMM: cx = x@Wx (hi/lo), reused as GEMM1 C-init for all 4 stages
    {
      short8 axh0 = ldsA<128>(xbh, l15, lq * 8);
      short8 axh1 = ldsA<128>(xbh, l15, 32 + lq * 8);
      short8 axl0 = ldsA<128>(xbl, l15, lq * 8);
      short8 axl1 = ldsA<128>(xbl, l15, 32 + lq * 8);
      #pragma unroll
      for (int nf = 0; nf < 8; ++nf){
        int f0 = ((      w * 8 + nf) * 2) * 64 + lane;
        int f1 = ((64 +  w * 8 + nf) * 2) * 64 + lane;
        short8 bh0 = Wxv[f0], bl0 = Wxv[f0 + 64];
        short8 bh1 = Wxv[f1], bl1 = Wxv[f1 + 64];
        f32x4 c = {0.f, 0.f, 0.f, 0.f};
        c = __builtin_amdgcn_mfma_f32_16x16x32_bf16(axh0, bh0, c, 0, 0, 0);
        c = __builtin_amdgcn_mfma_f32_16x16x32_bf16(axh0, bl0, c, 0, 0, 0);
        c = __builtin_amdgcn_mfma_f32_16x16x32_bf16(axl0, bh0, c, 0, 0, 0);
        c = __builtin_amdgcn_mfma_f32_16x16x32_bf16(axh1, bh1, c, 0, 0, 0);
        c = __builtin_amdgcn_mfma_f32_16x16x32_bf16(axh1, bl1, c, 0, 0, 0);
        c = __builtin_amdgcn_mfma_f32_16x16x32_bf16(axl1, bh1, c, 0, 0, 0);
        cx[nf] = c;
      }
    }

    #pragma unroll 1
    for (int s = 0; s < 4; ++s){
      const float ts = (s == 0) ? t0 : ((s == 3) ? t1 : t0 + 0.5f * hs);

      // ---- GEMM1: acc = z@W1 + cx (hi/lo), flattened q=(ks,nf), 1-deep B prefetch
      short8 azh[8], azl[8];
      #pragma unroll
      for (int ks = 0; ks < 8; ++ks){
        azh[ks] = ldsA<512>(zsh, l15, ks * 32 + lq * 8);
        azl[ks] = ldsA<512>(zsl, l15, ks * 32 + lq * 8);
      }
      f32x4 acc[8];
      #pragma unroll
      for (int nf = 0; nf < 8; ++nf) acc[nf] = cx[nf];
      short8 pbh[2], pbl[2];
      {
        int fi = ((w * 8) * 2) * 64 + lane;           // q=0 -> ks=0,nf=0
        pbh[0] = W1v[fi]; pbl[0] = W1v[fi + 64];
      }
      #pragma unroll
      for (int q = 0; q < 64; ++q){
        const int ks = q >> 3, nf = q & 7;
        if (q < 63){
          int qn = q + 1;
          int fi = (((qn >> 3) * 64 + w * 8 + (qn & 7)) * 2) * 64 + lane;
          pbh[qn & 1] = W1v[fi]; pbl[qn & 1] = W1v[fi + 64];
        }
        acc[nf] = __builtin_amdgcn_mfma_f32_16x16x32_bf16(azh[ks], pbh[q & 1], acc[nf], 0, 0, 0);
        acc[nf] = __builtin_amdgcn_mfma_f32_16x16x32_bf16(azh[ks], pbl[q & 1], acc[nf], 0, 0, 0);
        acc[nf] = __builtin_amdgcn_mfma_f32_16x16x32_bf16(azl[ks], pbh[q & 1], acc[nf], 0, 0, 0);
      }
      // epilogue: bias + tanh, write h hi/lo
      #pragma unroll
      for (int nf = 0; nf < 8; ++nf){
        float bias = b1r[nf] + ts * wtr[nf];
        #pragma unroll
        for (int i = 0; i < 4; ++i){
          float v = tanh_fast(acc[nf][i] + bias);
          unsigned short hh, ll; split_bf(v, hh, ll);
          ldsW16<2048>(hbh, lq * 4 + i, w * 128 + nf * 16 + l15, hh);
          ldsW16<2048>(hbl, lq * 4 + i, w * 128 + nf * 16 + l15, ll);
        }
      }
      __syncthreads();

      // ---- GEMM2: k = h@W2 + b2 (hi/lo), 1-deep prefetch ----
      f32x4 acc2[2];
      acc2[0] = f32x4{0.f, 0.f, 0.f, 0.f};
      acc2[1] = f32x4{0.f, 0.f, 0.f, 0.f};
      short8 ahh[2], ahl[2], bwh[2][2], bwl[2][2];
      ahh[0] = ldsA<2048>(hbh, l15, lq * 8);
      ahl[0] = ldsA<2048>(hbl, l15, lq * 8);
      #pragma unroll
      for (int n2 = 0; n2 < 2; ++n2){
        int fi = ((w * 2 + n2) * 2) * 64 + lane;      // ks=0
        bwh[0][n2] = W2v[fi]; bwl[0][n2] = W2v[fi + 64];
      }
      #pragma unroll
      for (int ks = 0; ks < 32; ++ks){
        const int cur = ks & 1, nxt = cur ^ 1;
        if (ks < 31){
          ahh[nxt] = ldsA<2048>(hbh, l15, (ks + 1) * 32 + lq * 8);
          ahl[nxt] = ldsA<2048>(hbl, l15, (ks + 1) * 32 + lq * 8);
          #pragma unroll
          for (int n2 = 0; n2 < 2; ++n2){
            int fi = (((ks + 1) * 16 + w * 2 + n2) * 2) * 64 + lane;
            bwh[nxt][n2] = W2v[fi]; bwl[nxt][n2] = W2v[fi + 64];
          }
        }
        #pragma unroll
        for (int n2 = 0; n2 < 2; ++n2){
          acc2[n2] = __builtin_amdgcn_mfma_f32_16x16x32_bf16(ahh[cur], bwh[cur][n2], acc2[n2], 0, 0, 0);
          acc2[n2] = __builtin_amdgcn_mfma_f32_16x16x32_bf16(ahh[cur], bwl[cur][n2], acc2[n2], 0, 0, 0);
          acc2[n2] = __builtin_amdgcn_mfma_f32_16x16x32_bf16(ahl[cur], bwh[cur][n2], acc2[n2], 0, 0, 0);
        }
      }

      // ---- RK4 update, write next-stage z hi/lo ----
      const float csw = (s == 0 || s == 3) ? 1.f : 2.f;
      const float dc  = (s < 2) ? 0.5f * hs : hs;
      #pragma unroll
      for (int n2 = 0; n2 < 2; ++n2){
        #pragma unroll
        for (int i = 0; i < 4; ++i){
          float kv = acc2[n2][i] + b2r[n2];
          za[n2][i] += csw * kv;
          float zn;
          if (s < 3){
            zn = zb[n2][i] + dc * kv;
          } else {
            zb[n2][i] += (hs * (1.f / 6.f)) * za[n2][i];
            za[n2][i] = 0.f;
            zn = zb[n2][i];
          }
          unsigned short hh, ll; split_bf(zn, hh, ll);
          ldsW16<512>(zsh, lq * 4 + i, w * 32 + n2 * 16 + l15, hh);
          ldsW16<512>(zsl, lq * 4 + i, w * 32 + n2 * 16 + l15, ll);
        }
      }
      __syncthreads();
    }
  }

  #pragma unroll
  for (int n2 = 0; n2 < 2; ++n2){
    #pragma unroll
    for (int i = 0; i < 4; ++i){
      int row = lq * 4 + i, col = w * 32 + n2 * 16 + l15;
      out[(rb * 16 + row) * DZ + col] = zb[n2][i];
    }
  }
}

// ---------------------------------------------------------------------------
// Fallback: the round-2 verified fp32 VALU kernel (used if ws_size too small).
// ---------------------------------------------------------------------------
typedef f32x4 f4;
__global__ __launch_bounds__(NT) void node_f32(
    const float* __restrict__ z0, const float* __restrict__ tt,
    const float* __restrict__ x,
    const float* __restrict__ W1, const float* __restrict__ Wx,
    const float* __restrict__ wt, const float* __restrict__ b1,
    const float* __restrict__ W2, const float* __restrict__ b2,
    float* __restrict__ out){
  const int wg = blockIdx.x, t = threadIdx.x;
  const int c0 = t, c1 = t + NT, c2 = t & 255, r0 = (t >> 8) * 4;
  __shared__ __align__(16) float zshm[8][260];
  __shared__ __align__(16) float hshm[8][1028];
  __shared__ __align__(16) float xshm[8][68];
  const float b1c0 = b1[c0], b1c1 = b1[c1], wtc0 = wt[c0], wtc1 = wt[c1], b2c = b2[c2];
  float zb[4], za[4];
  #pragma unroll
  for (int i = 0; i < 4; ++i){
    zb[i] = z0[(wg * 8 + r0 + i) * DZ + c2]; za[i] = 0.f; zshm[r0 + i][c2] = zb[i];
  }
  float cx0[8], cx1[8];
  for (int step = 0; step < NSTEP; ++step){
    const float t0 = tt[step], t1 = tt[step + 1], hs = t1 - t0;
    { int xr = t >> 6, xc = t & 63;
      xshm[xr][xc] = x[((size_t)step * 1024 + wg * 8 + xr) * DX + xc]; }
    __syncthreads();
    #pragma unroll
    for (int r = 0; r < 8; ++r){ cx0[r] = 0.f; cx1[r] = 0.f; }
    for (int k0 = 0; k0 < DX; k0 += 4){
      f4 xr4[8];
      #pragma unroll
      for (int r = 0; r < 8; ++r) xr4[r] = *(const f4*)&xshm[r][k0];
      float w0[4], w1[4];
      #pragma unroll
      for (int j = 0; j < 4; ++j){ w0[j] = Wx[(k0 + j) * DH + c0]; w1[j] = Wx[(k0 + j) * DH + c1]; }
      #pragma unroll
      for (int j = 0; j < 4; ++j)
        #pragma unroll
        for (int r = 0; r < 8; ++r){
          cx0[r] = fmaf(xr4[r][j], w0[j], cx0[r]); cx1[r] = fmaf(xr4[r][j], w1[j], cx1[r]); }
    }
    #pragma unroll 1
    for (int s = 0; s < 4; ++s){
      const float ts = (s == 0) ? t0 : ((s == 3) ? t1 : t0 + 0.5f * hs);
      float a0[8], a1[8];
      #pragma unroll
      for (int r = 0; r < 8; ++r){ a0[r] = cx0[r]; a1[r] = cx1[r]; }
      for (int k0 = 0; k0 < DZ; k0 += 4){
        f4 zr4[8];
        #pragma unroll
        for (int r = 0; r < 8; ++r) zr4[r] = *(const f4*)&zshm[r][k0];
        float w0[4], w1[4];
        #pragma unroll
        for (int j = 0; j < 4; ++j){ w0[j] = W1[(k0 + j) * DH + c0]; w1[j] = W1[(k0 + j) * DH + c1]; }
        #pragma unroll
        for (int j = 0; j < 4; ++j)
          #pragma unroll
          for (int r = 0; r < 8; ++r){
            a0[r] = fmaf(zr4[r][j], w0[j], a0[r]); a1[r] = fmaf(zr4[r][j], w1[j], a1[r]); }
      }
      const float bias0 = b1c0 + ts * wtc0, bias1 = b1c1 + ts * wtc1;
      #pragma unroll
      for (int r = 0; r < 8; ++r){
        hshm[r][c0] = tanh_fast(a0[r] + bias0); hshm[r][c1] = tanh_fast(a1[r] + bias1); }
      __syncthreads();
      float acc2[4] = {0.f, 0.f, 0.f, 0.f};
      for (int k0 = 0; k0 < DH; k0 += 4){
        f4 hr4[4];
        #pragma unroll
        for (int i = 0; i < 4; ++i) hr4[i] = *(const f4*)&hshm[r0 + i][k0];
        float w[4];
        #pragma unroll
        for (int j = 0; j < 4; ++j) w[j] = W2[(k0 + j) * DZ + c2];
        #pragma unroll
        for (int j = 0; j < 4; ++j)
          #pragma unroll
          for (int i = 0; i < 4; ++i) acc2[i] = fmaf(hr4[i][j], w[j], acc2[i]);
      }
      const float csw = (s == 0 || s == 3) ? 1.f : 2.f;
      const float dc = (s < 2) ? 0.5f * hs : hs;
      #pragma unroll
      for (int i = 0; i < 4; ++i){
        float kv = acc2[i] + b2c;
        za[i] += csw * kv;
        float zn;
        if (s < 3) zn = zb[i] + dc * kv;
        else { zb[i] += (hs * (1.f / 6.f)) * za[i]; za[i] = 0.f; zn = zb[i]; }
        zshm[r0 + i][c2] = zn;
      }
      __syncthreads();
    }
  }
  #pragma unroll
  for (int i = 0; i < 4; ++i) out[(wg * 8 + r0 + i) * DZ + c2] = zb[i];
}

extern "C" void kernel_launch(void* const* d_in, const int* in_sizes, int n_in,
                              void* d_out, int out_size, void* d_ws, size_t ws_size,
                              hipStream_t stream){
  const float* z0 = (const float*)d_in[0];
  const float* tt = (const float*)d_in[1];
  const float* x  = (const float*)d_in[2];
  const float* W1 = (const float*)d_in[3];
  const float* Wx = (const float*)d_in[4];
  const float* wt = (const float*)d_in[5];
  const float* b1 = (const float*)d_in[6];
  const float* W2 = (const float*)d_in[7];
  const float* b2 = (const float*)d_in[8];

  const size_t need = (size_t)(524288 + 524288 + 131072) * 2;   // 2.25 MB
  if (ws_size >= need){
    short* W1f = (short*)d_ws;
    short* W2f = W1f + 524288;
    short* Wxf = W2f + 524288;
    reformat_weights<<<288, 256, 0, stream>>>(W1, W2, Wx, W1f, W2f, Wxf);
    node_mfma<<<64, NT, 0, stream>>>(z0, tt, x, W1f, W2f, Wxf, wt, b1, b2, (float*)d_out);
  } else {
    node_f32<<<128, NT, 0, stream>>>(z0, tt, x, W1, Wx, wt, b1, W2, b2, (float*)d_out);
  }
}

// Round 4
// 9079.523 us; speedup vs baseline: 1.9179x; 1.9179x over previous
//
#include <hip/hip_runtime.h>

typedef __attribute__((ext_vector_type(8))) short short8;
typedef __attribute__((ext_vector_type(4))) float f32x4;
typedef __attribute__((ext_vector_type(4))) int   int4v;

#define NSTEP 63
#define DZ 256
#define DX 64
#define DH 1024
#define NT 512

__device__ __forceinline__ unsigned short f2bf(float f){
  unsigned u = __builtin_bit_cast(unsigned, f);
  u += 0x7fffu + ((u >> 16) & 1u);
  return (unsigned short)(u >> 16);
}
__device__ __forceinline__ float bf2f(unsigned short h){
  return __builtin_bit_cast(float, (unsigned)h << 16);
}
__device__ __forceinline__ void split_bf(float v, unsigned short& h, unsigned short& l){
  h = f2bf(v);
  l = f2bf(v - bf2f(h));
}
__device__ __forceinline__ float tanh_fast(float x){
  float e = __expf(2.0f * x);
  return 1.0f - 2.0f / (e + 1.0f);
}

// Swizzled LDS access (XOR byte ^= (row&7)<<4): breaks the bank conflicts of
// 512/2048-byte row strides on ds_read_b128; write/read use the same involution.
template<int ROWB>
__device__ __forceinline__ short8 ldsA(const short* buf, int row, int k0){
  int byte = row * ROWB + k0 * 2;
  byte ^= ((row & 7) << 4);
  return *reinterpret_cast<const short8*>(reinterpret_cast<const char*>(buf) + byte);
}
template<int ROWB>
__device__ __forceinline__ void ldsW16(short* buf, int row, int col, unsigned short v){
  int byte = row * ROWB + col * 2;
  byte ^= ((row & 7) << 4);
  *reinterpret_cast<short*>(reinterpret_cast<char*>(buf) + byte) = (short)v;
}

// On-the-fly Dekker split of 8 fp32 -> (hi, lo) bf16 short8 pair.
// v_cvt_pk_bf16_f32 is RTNE, so hi matches round-3's f2bf exactly; lo = v - hiF
// is exact (nearby subtraction), then RTNE again -> bit-identical to round 3.
__device__ __forceinline__ void cvt8(const float* v, short8& bh, short8& bl){
  int ph[4], pl[4];
  #pragma unroll
  for (int p = 0; p < 4; ++p){
    float a = v[2 * p], b = v[2 * p + 1];
    int hp;
    asm("v_cvt_pk_bf16_f32 %0, %1, %2" : "=v"(hp) : "v"(a), "v"(b));
    float fa = __builtin_bit_cast(float, hp << 16);
    float fb = __builtin_bit_cast(float, (unsigned)hp & 0xffff0000u);
    float la = a - fa, lb = b - fb;
    int lp;
    asm("v_cvt_pk_bf16_f32 %0, %1, %2" : "=v"(lp) : "v"(la), "v"(lb));
    ph[p] = hp; pl[p] = lp;
  }
  int4v vh = {ph[0], ph[1], ph[2], ph[3]};
  int4v vl = {pl[0], pl[1], pl[2], pl[3]};
  bh = __builtin_bit_cast(short8, vh);
  bl = __builtin_bit_cast(short8, vl);
}

// ---------------------------------------------------------------------------
// Split-precision MFMA NeuralODE, weights streamed fp32 from d_in (cache-
// resident per round-2 evidence) and split hi/lo on the fly. 64 WGs x 512 thr
// (8 waves); WG owns 16 batch rows, loops 63 steps x 4 RK4 stages locally.
//   GEMM1: wave w owns h-cols [128w,128w+128): 8ks x 8nf x 3 MFMAs.
//   GEMM2: wave w owns k-cols [32w,32w+32):  32ks x 2n2 x 3 MFMAs.
// K-panel loops are '#pragma unroll 1' to bound register pressure (round-3's
// 417 MB WRITE_SIZE was scratch spill traffic).
// ---------------------------------------------------------------------------
__global__ __launch_bounds__(NT, 1) void node_mfma(
    const float* __restrict__ z0, const float* __restrict__ tt,
    const float* __restrict__ x,
    const float* __restrict__ W1, const float* __restrict__ Wx,
    const float* __restrict__ W2,
    const float* __restrict__ wt, const float* __restrict__ b1,
    const float* __restrict__ b2, float* __restrict__ out){

  const int rb   = blockIdx.x;
  const int tid  = threadIdx.x;
  const int w    = tid >> 6;
  const int lane = tid & 63;
  const int l15  = lane & 15;
  const int lq   = lane >> 4;

  __shared__ __align__(16) short zsh[16 * DZ], zsl[16 * DZ];   // 8 KB each
  __shared__ __align__(16) short hbh[16 * DH], hbl[16 * DH];   // 32 KB each
  __shared__ __align__(16) short xbh[16 * DX], xbl[16 * DX];   // 2 KB each

  float b1r[8], wtr[8];
  #pragma unroll
  for (int nf = 0; nf < 8; ++nf){
    int c = w * 128 + nf * 16 + l15;
    b1r[nf] = b1[c]; wtr[nf] = wt[c];
  }
  float b2r[2];
  #pragma unroll
  for (int n2 = 0; n2 < 2; ++n2) b2r[n2] = b2[w * 32 + n2 * 16 + l15];

  float zb[2][4], za[2][4];
  #pragma unroll
  for (int n2 = 0; n2 < 2; ++n2){
    #pragma unroll
    for (int i = 0; i < 4; ++i){
      int row = lq * 4 + i, col = w * 32 + n2 * 16 + l15;
      zb[n2][i] = z0[(rb * 16 + row) * DZ + col];
      za[n2][i] = 0.f;
      unsigned short h, l; split_bf(zb[n2][i], h, l);
      ldsW16<512>(zsh, row, col, h);
      ldsW16<512>(zsl, row, col, l);
    }
  }

  f32x4 cx[8];

  for (int step = 0; step < NSTEP; ++step){
    const float t0 = tt[step], t1 = tt[step + 1];
    const float hs = t1 - t0;

    // stage x[step] (hi/lo bf16, swizzled): 512 thr x 2 elems
    {
      int e  = tid * 2;
      int xr = e >> 6, xc = e & 63;
      const float* xp = x + ((size_t)step * 1024 + rb * 16 + xr) * DX + xc;
      unsigned short h0, l0, h1, l1;
      split_bf(xp[0], h0, l0); split_bf(xp[1], h1, l1);
      int byte = xr * 128 + xc * 2;
      byte ^= ((xr & 7) << 4);
      *reinterpret_cast<unsigned*>(reinterpret_cast<char*>(xbh) + byte) =
          (unsigned)h0 | ((unsigned)h1 << 16);
      *reinterpret_cast<unsigned*>(reinterpret_cast<char*>(xbl) + byte) =
          (unsigned)l0 | ((unsigned)l1 << 16);
    }
    __syncthreads();

    // x-GEMM: cx = x@Wx (hi/lo, on-the-fly W split), C-init for all 4 stages
    {
      short8 axh0 = ldsA<128>(xbh, l15, lq * 8);
      short8 axh1 = ldsA<128>(xbh, l15, 32 + lq * 8);
      short8 axl0 = ldsA<128>(xbl, l15, lq * 8);
      short8 axl1 = ldsA<128>(xbl, l15, 32 + lq * 8);
      const float* wxp = Wx + (size_t)(lq * 8) * DH + w * 128 + l15;
      #pragma unroll
      for (int nf = 0; nf < 8; ++nf){
        float wv[8];
        short8 bh, bl;
        f32x4 c = {0.f, 0.f, 0.f, 0.f};
        #pragma unroll
        for (int j = 0; j < 8; ++j) wv[j] = wxp[(size_t)j * DH + nf * 16];
        cvt8(wv, bh, bl);
        c = __builtin_amdgcn_mfma_f32_16x16x32_bf16(axh0, bh, c, 0, 0, 0);
        c = __builtin_amdgcn_mfma_f32_16x16x32_bf16(axh0, bl, c, 0, 0, 0);
        c = __builtin_amdgcn_mfma_f32_16x16x32_bf16(axl0, bh, c, 0, 0, 0);
        #pragma unroll
        for (int j = 0; j < 8; ++j) wv[j] = wxp[(size_t)(32 + j) * DH + nf * 16];
        cvt8(wv, bh, bl);
        c = __builtin_amdgcn_mfma_f32_16x16x32_bf16(axh1, bh, c, 0, 0, 0);
        c = __builtin_amdgcn_mfma_f32_16x16x32_bf16(axh1, bl, c, 0, 0, 0);
        c = __builtin_amdgcn_mfma_f32_16x16x32_bf16(axl1, bh, c, 0, 0, 0);
        cx[nf] = c;
      }
    }

    #pragma unroll 1
    for (int s = 0; s < 4; ++s){
      const float ts = (s == 0) ? t0 : ((s == 3) ? t1 : t0 + 0.5f * hs);

      // ---- GEMM1: acc = z@W1 + cx ----
      f32x4 acc[8];
      #pragma unroll
      for (int nf = 0; nf < 8; ++nf) acc[nf] = cx[nf];
      #pragma unroll 1
      for (int ks = 0; ks < 8; ++ks){
        short8 azh = ldsA<512>(zsh, l15, ks * 32 + lq * 8);
        short8 azl = ldsA<512>(zsl, l15, ks * 32 + lq * 8);
        const float* wp = W1 + (size_t)(ks * 32 + lq * 8) * DH + w * 128 + l15;
        #pragma unroll
        for (int nf = 0; nf < 8; ++nf){
          float wv[8];
          #pragma unroll
          for (int j = 0; j < 8; ++j) wv[j] = wp[(size_t)j * DH + nf * 16];
          short8 bh, bl;
          cvt8(wv, bh, bl);
          acc[nf] = __builtin_amdgcn_mfma_f32_16x16x32_bf16(azh, bh, acc[nf], 0, 0, 0);
          acc[nf] = __builtin_amdgcn_mfma_f32_16x16x32_bf16(azh, bl, acc[nf], 0, 0, 0);
          acc[nf] = __builtin_amdgcn_mfma_f32_16x16x32_bf16(azl, bh, acc[nf], 0, 0, 0);
        }
      }
      // epilogue: bias + tanh, write h hi/lo
      #pragma unroll
      for (int nf = 0; nf < 8; ++nf){
        float bias = b1r[nf] + ts * wtr[nf];
        #pragma unroll
        for (int i = 0; i < 4; ++i){
          float v = tanh_fast(acc[nf][i] + bias);
          unsigned short hh, ll; split_bf(v, hh, ll);
          ldsW16<2048>(hbh, lq * 4 + i, w * 128 + nf * 16 + l15, hh);
          ldsW16<2048>(hbl, lq * 4 + i, w * 128 + nf * 16 + l15, ll);
        }
      }
      __syncthreads();

      // ---- GEMM2: k = h@W2 + b2 ----
      f32x4 acc2[2];
      acc2[0] = f32x4{0.f, 0.f, 0.f, 0.f};
      acc2[1] = f32x4{0.f, 0.f, 0.f, 0.f};
      #pragma unroll 1
      for (int ks = 0; ks < 32; ++ks){
        short8 ahh = ldsA<2048>(hbh, l15, ks * 32 + lq * 8);
        short8 ahl = ldsA<2048>(hbl, l15, ks * 32 + lq * 8);
        const float* w2p = W2 + (size_t)(ks * 32 + lq * 8) * DZ + w * 32 + l15;
        #pragma unroll
        for (int n2 = 0; n2 < 2; ++n2){
          float wv[8];
          #pragma unroll
          for (int j = 0; j < 8; ++j) wv[j] = w2p[(size_t)j * DZ + n2 * 16];
          short8 bh, bl;
          cvt8(wv, bh, bl);
          acc2[n2] = __builtin_amdgcn_mfma_f32_16x16x32_bf16(ahh, bh, acc2[n2], 0, 0, 0);
          acc2[n2] = __builtin_amdgcn_mfma_f32_16x16x32_bf16(ahh, bl, acc2[n2], 0, 0, 0);
          acc2[n2] = __builtin_amdgcn_mfma_f32_16x16x32_bf16(ahl, bh, acc2[n2], 0, 0, 0);
        }
      }

      // ---- RK4 update, write next-stage z hi/lo ----
      const float csw = (s == 0 || s == 3) ? 1.f : 2.f;
      const float dc  = (s < 2) ? 0.5f * hs : hs;
      #pragma unroll
      for (int n2 = 0; n2 < 2; ++n2){
        #pragma unroll
        for (int i = 0; i < 4; ++i){
          float kv = acc2[n2][i] + b2r[n2];
          za[n2][i] += csw * kv;
          float zn;
          if (s < 3){
            zn = zb[n2][i] + dc * kv;
          } else {
            zb[n2][i] += (hs * (1.f / 6.f)) * za[n2][i];
            za[n2][i] = 0.f;
            zn = zb[n2][i];
          }
          unsigned short hh, ll; split_bf(zn, hh, ll);
          ldsW16<512>(zsh, lq * 4 + i, w * 32 + n2 * 16 + l15, hh);
          ldsW16<512>(zsl, lq * 4 + i, w * 32 + n2 * 16 + l15, ll);
        }
      }
      __syncthreads();
    }
  }

  #pragma unroll
  for (int n2 = 0; n2 < 2; ++n2){
    #pragma unroll
    for (int i = 0; i < 4; ++i){
      int row = lq * 4 + i, col = w * 32 + n2 * 16 + l15;
      out[(rb * 16 + row) * DZ + col] = zb[n2][i];
    }
  }
}

extern "C" void kernel_launch(void* const* d_in, const int* in_sizes, int n_in,
                              void* d_out, int out_size, void* d_ws, size_t ws_size,
                              hipStream_t stream){
  const float* z0 = (const float*)d_in[0];
  const float* tt = (const float*)d_in[1];
  const float* x  = (const float*)d_in[2];
  const float* W1 = (const float*)d_in[3];
  const float* Wx = (const float*)d_in[4];
  const float* wt = (const float*)d_in[5];
  const float* b1 = (const float*)d_in[6];
  const float* W2 = (const float*)d_in[7];
  const float* b2 = (const float*)d_in[8];

  node_mfma<<<64, NT, 0, stream>>>(z0, tt, x, W1, Wx, W2, wt, b1, b2, (float*)d_out);
}

// Round 5
// 4548.896 us; speedup vs baseline: 3.8281x; 1.9960x over previous
//
#include <hip/hip_runtime.h>

typedef __attribute__((ext_vector_type(8))) short short8;
typedef __attribute__((ext_vector_type(4))) float f32x4;

#define NSTEP 63
#define DZ 256
#define DX 64
#define DH 1024
#define NT 1024

__device__ __forceinline__ unsigned short f2bf(float f){
  unsigned u = __builtin_bit_cast(unsigned, f);
  u += 0x7fffu + ((u >> 16) & 1u);
  return (unsigned short)(u >> 16);
}
__device__ __forceinline__ float bf2f(unsigned short h){
  return __builtin_bit_cast(float, (unsigned)h << 16);
}
__device__ __forceinline__ void split_bf(float v, unsigned short& h, unsigned short& l){
  h = f2bf(v);
  l = f2bf(v - bf2f(h));
}
__device__ __forceinline__ float tanh_fast(float x){
  float e = __expf(2.0f * x);
  return 1.0f - 2.0f / (e + 1.0f);
}
// packed bf16 pair: low16 = bf16(a), high16 = bf16(b)  (RTNE, matches f2bf)
__device__ __forceinline__ unsigned pk2(float a, float b){
  int r; asm("v_cvt_pk_bf16_f32 %0, %1, %2" : "=v"(r) : "v"(a), "v"(b));
  return (unsigned)r;
}
// 4 floats -> (hi u64, lo u64) of 4 bf16 each (cols c..c+3 order)
__device__ __forceinline__ void pack4(const float* v, unsigned long long& hi,
                                      unsigned long long& lo){
  unsigned h0 = pk2(v[0], v[1]), h1 = pk2(v[2], v[3]);
  float f0 = __builtin_bit_cast(float, h0 << 16);
  float f1 = __builtin_bit_cast(float, h0 & 0xffff0000u);
  float f2 = __builtin_bit_cast(float, h1 << 16);
  float f3 = __builtin_bit_cast(float, h1 & 0xffff0000u);
  unsigned l0 = pk2(v[0] - f0, v[1] - f1), l1 = pk2(v[2] - f2, v[3] - f3);
  hi = (unsigned long long)h0 | ((unsigned long long)h1 << 32);
  lo = (unsigned long long)l0 | ((unsigned long long)l1 << 32);
}

// Swizzled LDS access (XOR byte ^= (row&7)<<4): breaks bank conflicts of
// 512/2048-byte row strides; all accesses (b64 write, b128 read) use the same
// involution, and the XOR (multiple of 16) preserves 8/16B alignment.
template<int ROWB>
__device__ __forceinline__ short8 ldsA(const short* buf, int row, int k0){
  int byte = row * ROWB + k0 * 2;
  byte ^= ((row & 7) << 4);
  return *reinterpret_cast<const short8*>(reinterpret_cast<const char*>(buf) + byte);
}
template<int ROWB>
__device__ __forceinline__ void ldsW64(short* buf, int row, int col, unsigned long long v){
  int byte = row * ROWB + col * 2;
  byte ^= ((row & 7) << 4);
  *reinterpret_cast<unsigned long long*>(reinterpret_cast<char*>(buf) + byte) = v;
}

// ---------------------------------------------------------------------------
// Reformat weights into hi/lo bf16 MFMA fragment pairs (validated round 3):
//   frag(ks,nblk,p): lane l, elem j holds W[k=32ks+8(l>>4)+j][col=16nblk+(l&15)]
//   short8 index: ((ks*NB + nblk)*2 + p)*64 + lane      (p=0 hi, p=1 lo)
// Used as MFMA *A*-operand (operand-swapped GEMM): A[m=l&15][k] = W[k][col=m].
// ---------------------------------------------------------------------------
__global__ void reformat_weights(const float* __restrict__ W1,
                                 const float* __restrict__ W2,
                                 const float* __restrict__ Wx,
                                 short* __restrict__ W1f,
                                 short* __restrict__ W2f,
                                 short* __restrict__ Wxf){
  int tid = blockIdx.x * 256 + threadIdx.x;
  if (tid < 32768){                       // W1: ks 0..7, nblk 0..63
    int lane = tid & 63, nblk = (tid >> 6) & 63, ks = tid >> 12;
    int k0 = ks * 32 + (lane >> 4) * 8, col = nblk * 16 + (lane & 15);
    short8 vh, vl;
    #pragma unroll
    for (int j = 0; j < 8; ++j){
      unsigned short h, l; split_bf(W1[(k0 + j) * DH + col], h, l);
      vh[j] = (short)h; vl[j] = (short)l;
    }
    int base = ((ks * 64 + nblk) * 2) * 64 + lane;
    reinterpret_cast<short8*>(W1f)[base]      = vh;
    reinterpret_cast<short8*>(W1f)[base + 64] = vl;
  } else if (tid < 65536){                // W2: ks 0..31, nblk 0..15
    int t = tid - 32768;
    int lane = t & 63, nblk = (t >> 6) & 15, ks = t >> 10;
    int k0 = ks * 32 + (lane >> 4) * 8, col = nblk * 16 + (lane & 15);
    short8 vh, vl;
    #pragma unroll
    for (int j = 0; j < 8; ++j){
      unsigned short h, l; split_bf(W2[(k0 + j) * DZ + col], h, l);
      vh[j] = (short)h; vl[j] = (short)l;
    }
    int base = ((ks * 16 + nblk) * 2) * 64 + lane;
    reinterpret_cast<short8*>(W2f)[base]      = vh;
    reinterpret_cast<short8*>(W2f)[base + 64] = vl;
  } else if (tid < 73728){                // Wx: ks 0..1, nblk 0..63
    int t = tid - 65536;
    int lane = t & 63, nblk = (t >> 6) & 63, ks = t >> 12;
    int k0 = ks * 32 + (lane >> 4) * 8, col = nblk * 16 + (lane & 15);
    short8 vh, vl;
    #pragma unroll
    for (int j = 0; j < 8; ++j){
      unsigned short h, l; split_bf(Wx[(k0 + j) * DH + col], h, l);
      vh[j] = (short)h; vl[j] = (short)l;
    }
    int base = ((ks * 64 + nblk) * 2) * 64 + lane;
    reinterpret_cast<short8*>(Wxf)[base]      = vh;
    reinterpret_cast<short8*>(Wxf)[base + 64] = vl;
  }
}

// ---------------------------------------------------------------------------
// Split-precision MFMA NeuralODE, operand-swapped: D = mfma(A=W_frag, B=z_frag)
// -> D[m = 4 consecutive out-cols][n = batch row (lane&15)]. 64 WGs x 1024 thr
// (16 waves, 4/SIMD); WG owns 16 batch rows, 63 steps x 4 RK4 stages local.
//   GEMM1: wave w owns h-cols [64w,64w+64):  8ks x 4nf x 3 = 96 MFMAs.
//   GEMM2: wave w owns k-cols [16w,16w+16): 32ks x 1   x 3 = 96 MFMAs.
// All LDS writes are b64 (4 bf16), all state/output stores dwordx4.
// ---------------------------------------------------------------------------
__global__ __launch_bounds__(NT, 1) void node_mfma(
    const float* __restrict__ z0, const float* __restrict__ tt,
    const float* __restrict__ x,
    const short* __restrict__ W1f, const short* __restrict__ W2f,
    const short* __restrict__ Wxf,
    const float* __restrict__ wt, const float* __restrict__ b1,
    const float* __restrict__ b2, float* __restrict__ out){

  const int rb   = blockIdx.x;
  const int tid  = threadIdx.x;
  const int w    = tid >> 6;         // wave 0..15
  const int lane = tid & 63;
  const int l15  = lane & 15;        // batch row within block
  const int lq   = lane >> 4;        // out-col quad selector

  __shared__ __align__(16) short zsh[16 * DZ], zsl[16 * DZ];   // 8 KB each
  __shared__ __align__(16) short hbh[16 * DH], hbl[16 * DH];   // 32 KB each
  __shared__ __align__(16) short xbh[16 * DX], xbl[16 * DX];   // 2 KB each
  __shared__ __align__(16) float b1l[DH], wtl[DH];             // 4 KB each

  const short8* W1v = reinterpret_cast<const short8*>(W1f);
  const short8* W2v = reinterpret_cast<const short8*>(W2f);
  const short8* Wxv = reinterpret_cast<const short8*>(Wxf);

  b1l[tid] = b1[tid];
  wtl[tid] = wt[tid];

  // per-lane GEMM2 bias: 4 consecutive k-cols
  const f32x4 b2r = *reinterpret_cast<const f32x4*>(b2 + w * 16 + lq * 4);

  // z state: batch row l15, cols w*16 + lq*4 .. +3
  f32x4 zb, za = {0.f, 0.f, 0.f, 0.f};
  {
    zb = *reinterpret_cast<const f32x4*>(z0 + (rb * 16 + l15) * DZ + w * 16 + lq * 4);
    unsigned long long hi, lo;
    pack4((const float*)&zb, hi, lo);
    ldsW64<512>(zsh, l15, w * 16 + lq * 4, hi);
    ldsW64<512>(zsl, l15, w * 16 + lq * 4, lo);
  }

  f32x4 cx[4];

  for (int step = 0; step < NSTEP; ++step){
    const float t0 = tt[step], t1 = tt[step + 1];
    const float hs = t1 - t0;

    // stage x[step] (hi/lo bf16, swizzled): 512 low threads x 2 elems
    if (tid < 512){
      int e  = tid * 2;
      int xr = e >> 6, xc = e & 63;
      const float* xp = x + ((size_t)step * 1024 + rb * 16 + xr) * DX + xc;
      unsigned short h0, l0, h1, l1;
      split_bf(xp[0], h0, l0); split_bf(xp[1], h1, l1);
      int byte = (xr * 128 + xc * 2) ^ ((xr & 7) << 4);
      *reinterpret_cast<unsigned*>(reinterpret_cast<char*>(xbh) + byte) =
          (unsigned)h0 | ((unsigned)h1 << 16);
      *reinterpret_cast<unsigned*>(reinterpret_cast<char*>(xbl) + byte) =
          (unsigned)l0 | ((unsigned)l1 << 16);
    }
    __syncthreads();

    // x-GEMM: cx = x@Wx (C-init for all 4 stages), operand-swapped
    {
      short8 axh0 = ldsA<128>(xbh, l15, lq * 8);
      short8 axh1 = ldsA<128>(xbh, l15, 32 + lq * 8);
      short8 axl0 = ldsA<128>(xbl, l15, lq * 8);
      short8 axl1 = ldsA<128>(xbl, l15, 32 + lq * 8);
      #pragma unroll
      for (int nf = 0; nf < 4; ++nf){
        int f0 = ((      w * 4 + nf) * 2) * 64 + lane;
        int f1 = ((64 +  w * 4 + nf) * 2) * 64 + lane;
        short8 wh0 = Wxv[f0], wl0 = Wxv[f0 + 64];
        short8 wh1 = Wxv[f1], wl1 = Wxv[f1 + 64];
        f32x4 c = {0.f, 0.f, 0.f, 0.f};
        c = __builtin_amdgcn_mfma_f32_16x16x32_bf16(wh0, axh0, c, 0, 0, 0);
        c = __builtin_amdgcn_mfma_f32_16x16x32_bf16(wl0, axh0, c, 0, 0, 0);
        c = __builtin_amdgcn_mfma_f32_16x16x32_bf16(wh0, axl0, c, 0, 0, 0);
        c = __builtin_amdgcn_mfma_f32_16x16x32_bf16(wh1, axh1, c, 0, 0, 0);
        c = __builtin_amdgcn_mfma_f32_16x16x32_bf16(wl1, axh1, c, 0, 0, 0);
        c = __builtin_amdgcn_mfma_f32_16x16x32_bf16(wh1, axl1, c, 0, 0, 0);
        cx[nf] = c;
      }
    }

    #pragma unroll 1
    for (int s = 0; s < 4; ++s){
      const float ts = (s == 0) ? t0 : ((s == 3) ? t1 : t0 + 0.5f * hs);

      // ---- GEMM1: acc = z@W1 + cx ----
      f32x4 acc[4];
      #pragma unroll
      for (int nf = 0; nf < 4; ++nf) acc[nf] = cx[nf];
      #pragma unroll 1
      for (int ks = 0; ks < 8; ++ks){
        short8 azh = ldsA<512>(zsh, l15, ks * 32 + lq * 8);
        short8 azl = ldsA<512>(zsl, l15, ks * 32 + lq * 8);
        #pragma unroll
        for (int nf = 0; nf < 4; ++nf){
          int fi = ((ks * 64 + w * 4 + nf) * 2) * 64 + lane;
          short8 wh = W1v[fi], wl = W1v[fi + 64];
          acc[nf] = __builtin_amdgcn_mfma_f32_16x16x32_bf16(wh, azh, acc[nf], 0, 0, 0);
          acc[nf] = __builtin_amdgcn_mfma_f32_16x16x32_bf16(wl, azh, acc[nf], 0, 0, 0);
          acc[nf] = __builtin_amdgcn_mfma_f32_16x16x32_bf16(wh, azl, acc[nf], 0, 0, 0);
        }
      }
      // epilogue: bias + tanh, pack, b64 writes to h (lane owns 4 cols, row l15)
      #pragma unroll
      for (int nf = 0; nf < 4; ++nf){
        int cb = w * 64 + nf * 16 + lq * 4;
        f32x4 b1v = *reinterpret_cast<const f32x4*>(&b1l[cb]);
        f32x4 wtv = *reinterpret_cast<const f32x4*>(&wtl[cb]);
        float v[4];
        #pragma unroll
        for (int i = 0; i < 4; ++i)
          v[i] = tanh_fast(acc[nf][i] + b1v[i] + ts * wtv[i]);
        unsigned long long hi, lo;
        pack4(v, hi, lo);
        ldsW64<2048>(hbh, l15, cb, hi);
        ldsW64<2048>(hbl, l15, cb, lo);
      }
      __syncthreads();

      // ---- GEMM2: k = h@W2 + b2, 1-deep rotated prefetch ----
      f32x4 acc2 = {0.f, 0.f, 0.f, 0.f};
      short8 ahh = ldsA<2048>(hbh, l15, lq * 8);
      short8 ahl = ldsA<2048>(hbl, l15, lq * 8);
      short8 wh  = W2v[((w) * 2) * 64 + lane];
      short8 wl  = W2v[((w) * 2) * 64 + lane + 64];
      #pragma unroll 1
      for (int ks = 0; ks < 32; ++ks){
        short8 nahh, nahl, nwh, nwl;
        if (ks < 31){
          nahh = ldsA<2048>(hbh, l15, (ks + 1) * 32 + lq * 8);
          nahl = ldsA<2048>(hbl, l15, (ks + 1) * 32 + lq * 8);
          int fi = (((ks + 1) * 16 + w) * 2) * 64 + lane;
          nwh = W2v[fi]; nwl = W2v[fi + 64];
        }
        acc2 = __builtin_amdgcn_mfma_f32_16x16x32_bf16(wh, ahh, acc2, 0, 0, 0);
        acc2 = __builtin_amdgcn_mfma_f32_16x16x32_bf16(wl, ahh, acc2, 0, 0, 0);
        acc2 = __builtin_amdgcn_mfma_f32_16x16x32_bf16(wh, ahl, acc2, 0, 0, 0);
        ahh = nahh; ahl = nahl; wh = nwh; wl = nwl;
      }

      // ---- RK4 update, pack, b64 writes of next-stage z ----
      const float csw = (s == 0 || s == 3) ? 1.f : 2.f;
      const float dc  = (s < 2) ? 0.5f * hs : hs;
      float zn[4];
      #pragma unroll
      for (int i = 0; i < 4; ++i){
        float kv = acc2[i] + b2r[i];
        za[i] += csw * kv;
        if (s < 3){
          zn[i] = zb[i] + dc * kv;
        } else {
          zb[i] += (hs * (1.f / 6.f)) * za[i];
          za[i] = 0.f;
          zn[i] = zb[i];
        }
      }
      unsigned long long hi, lo;
      pack4(zn, hi, lo);
      ldsW64<512>(zsh, l15, w * 16 + lq * 4, hi);
      ldsW64<512>(zsl, l15, w * 16 + lq * 4, lo);
      __syncthreads();
    }
  }

  // final write: 16B per lane, row l15
  *reinterpret_cast<f32x4*>(out + (rb * 16 + l15) * DZ + w * 16 + lq * 4) = zb;
}

extern "C" void kernel_launch(void* const* d_in, const int* in_sizes, int n_in,
                              void* d_out, int out_size, void* d_ws, size_t ws_size,
                              hipStream_t stream){
  const float* z0 = (const float*)d_in[0];
  const float* tt = (const float*)d_in[1];
  const float* x  = (const float*)d_in[2];
  const float* W1 = (const float*)d_in[3];
  const float* Wx = (const float*)d_in[4];
  const float* wt = (const float*)d_in[5];
  const float* b1 = (const float*)d_in[6];
  const float* W2 = (const float*)d_in[7];
  const float* b2 = (const float*)d_in[8];

  short* W1f = (short*)d_ws;          // 524288 shorts (1 MB)
  short* W2f = W1f + 524288;          // 524288 shorts (1 MB)
  short* Wxf = W2f + 524288;          // 131072 shorts (256 KB)

  reformat_weights<<<288, 256, 0, stream>>>(W1, W2, Wx, W1f, W2f, Wxf);
  node_mfma<<<64, NT, 0, stream>>>(z0, tt, x, W1f, W2f, Wxf, wt, b1, b2, (float*)d_out);
}